// Round 1
// baseline (884.930 us; speedup 1.0000x reference)
//
#include <hip/hip_runtime.h>
#include <math.h>

// VQQuantizer eval path.
// h: [32768, 512] f32, codebook: [1024, 512] f32 (pre-normalized, re-normalized here).
// Outputs (f32, concatenated): q [32768,1024], c_tilde [32768,512], c_hard, c_quantized,
// loss (1), indices (32768, written as float).
//
// Key decision: all distance math accumulated in fp64 so argmin matches the harness's
// float64 numpy reference exactly (a single argmin flip fails the absmax threshold).

#define NROWS 32768
#define DDIM  512
#define KCODE 1024

// ---------------- inverse norms (one wave per row) ----------------
__global__ __launch_bounds__(256) void k_inv_norms(const float* __restrict__ x,
                                                   double* __restrict__ inv, int rows) {
  const int lane = threadIdx.x & 63;
  const int row = blockIdx.x * 4 + (threadIdx.x >> 6);
  if (row >= rows) return;
  const float* p = x + (size_t)row * DDIM;
  float4 v0 = *(const float4*)(p + lane * 4);
  float4 v1 = *(const float4*)(p + 256 + lane * 4);
  double s = (double)v0.x * (double)v0.x + (double)v0.y * (double)v0.y
           + (double)v0.z * (double)v0.z + (double)v0.w * (double)v0.w
           + (double)v1.x * (double)v1.x + (double)v1.y * (double)v1.y
           + (double)v1.z * (double)v1.z + (double)v1.w * (double)v1.w;
  #pragma unroll
  for (int m = 1; m < 64; m <<= 1) s += __shfl_xor(s, m);
  if (lane == 0) inv[row] = 1.0 / fmax(sqrt(s), 1e-6);
}

// ---------------- fp64-accumulated score GEMM + per-stripe argmax ----------------
// Block: 256 threads. Tile: 32 rows x 256 codes. K staged in chunks of 32.
// Thread (wave wv, lane) owns rows [wv*8, wv*8+8) x codes [lane*4, lane*4+4).
__global__ __launch_bounds__(256) void k_scores(const float* __restrict__ h,
                                                const float* __restrict__ cb,
                                                const double* __restrict__ invc,
                                                double* __restrict__ pscore,
                                                int* __restrict__ pidx) {
  __shared__ float aT[32][32];   // [dk][row]  4 KB
  __shared__ float bT[32][256];  // [dk][code] 32 KB
  const int tx = threadIdx.x;
  const int tilec = blockIdx.x & 3;   // 4 code stripes of 256
  const int tiler = blockIdx.x >> 2;  // 1024 row tiles of 32
  const int row0 = tiler * 32;
  const int col0 = tilec * 256;
  const int lane = tx & 63;
  const int wv = tx >> 6;
  const int r0 = wv * 8;
  const int c0 = lane * 4;

  double acc[8][4];
  #pragma unroll
  for (int r = 0; r < 8; ++r)
    #pragma unroll
    for (int c = 0; c < 4; ++c) acc[r][c] = 0.0;

  const int ra = tx >> 3;
  const int dka = (tx & 7) * 4;

  for (int k0 = 0; k0 < DDIM; k0 += 32) {
    __syncthreads();
    // stage A (32x32): one float4 per thread, coalesced
    {
      float4 va = *(const float4*)(&h[(size_t)(row0 + ra) * DDIM + k0 + dka]);
      aT[dka + 0][ra] = va.x; aT[dka + 1][ra] = va.y;
      aT[dka + 2][ra] = va.z; aT[dka + 3][ra] = va.w;
    }
    // stage B (256x32): 8 float4 per thread, coalesced
    #pragma unroll
    for (int j = 0; j < 8; ++j) {
      int i = tx + j * 256;
      int cc = i >> 3;
      int dk = (i & 7) * 4;
      float4 vb = *(const float4*)(&cb[(size_t)(col0 + cc) * DDIM + k0 + dk]);
      bT[dk + 0][cc] = vb.x; bT[dk + 1][cc] = vb.y;
      bT[dk + 2][cc] = vb.z; bT[dk + 3][cc] = vb.w;
    }
    __syncthreads();
    #pragma unroll
    for (int kk = 0; kk < 32; ++kk) {
      float4 a0 = *(const float4*)(&aT[kk][r0]);
      float4 a1 = *(const float4*)(&aT[kk][r0 + 4]);
      float4 b0 = *(const float4*)(&bT[kk][c0]);
      double ad[8] = {(double)a0.x, (double)a0.y, (double)a0.z, (double)a0.w,
                      (double)a1.x, (double)a1.y, (double)a1.z, (double)a1.w};
      double bd[4] = {(double)b0.x, (double)b0.y, (double)b0.z, (double)b0.w};
      #pragma unroll
      for (int r = 0; r < 8; ++r)
        #pragma unroll
        for (int c = 0; c < 4; ++c)
          acc[r][c] = fma(ad[r], bd[c], acc[r][c]);
    }
  }

  // score = dot * invc ; per-row argmax across this 256-code stripe
  double vinv[4];
  #pragma unroll
  for (int c = 0; c < 4; ++c) vinv[c] = invc[col0 + c0 + c];

  #pragma unroll
  for (int r = 0; r < 8; ++r) {
    double bs = -1e300; int bi = 0x7fffffff;
    #pragma unroll
    for (int c = 0; c < 4; ++c) {
      double s = acc[r][c] * vinv[c];
      if (s > bs) { bs = s; bi = col0 + c0 + c; }   // ascending c: ties keep first
    }
    #pragma unroll
    for (int m = 1; m < 64; m <<= 1) {
      double os = __shfl_xor(bs, m);
      int oi = __shfl_xor(bi, m);
      if (os > bs || (os == bs && oi < bi)) { bs = os; bi = oi; }
    }
    if (lane == 0) {
      int row = row0 + r0 + r;
      pscore[row * 4 + tilec] = bs;
      pidx[row * 4 + tilec] = bi;
    }
  }
}

// ---------------- epilogue: one block per row ----------------
__global__ __launch_bounds__(256) void k_finalize(const float* __restrict__ h,
                                                  const float* __restrict__ cb,
                                                  const double* __restrict__ invc,
                                                  const double* __restrict__ pscore,
                                                  const int* __restrict__ pidx,
                                                  float* __restrict__ out_q,
                                                  float* __restrict__ out_ct,
                                                  float* __restrict__ out_ch,
                                                  float* __restrict__ out_cq,
                                                  float* __restrict__ out_idx,
                                                  double* __restrict__ lsum) {
  const int n = blockIdx.x;
  const int tx = threadIdx.x;
  const int lane = tx & 63;
  const int wv = tx >> 6;
  __shared__ double sh[8];

  // row norm of h (fp64)
  const int d0 = tx * 2;
  float2 hv = *(const float2*)(&h[(size_t)n * DDIM + d0]);
  double hs = (double)hv.x * (double)hv.x + (double)hv.y * (double)hv.y;
  #pragma unroll
  for (int m = 1; m < 64; m <<= 1) hs += __shfl_xor(hs, m);
  if (lane == 0) sh[wv] = hs;
  __syncthreads();
  const double ih = 1.0 / fmax(sqrt(sh[0] + sh[1] + sh[2] + sh[3]), 1e-6);

  // best index over the 4 stripes (stripes ascend in code index; strict > keeps first)
  double bs = pscore[n * 4]; int bi = pidx[n * 4];
  #pragma unroll
  for (int t = 1; t < 4; ++t) {
    double s = pscore[n * 4 + t]; int ii = pidx[n * 4 + t];
    if (s > bs) { bs = s; bi = ii; }
  }
  if (tx == 0) out_idx[n] = (float)bi;

  // c rows (all three outputs identical in eval path) + loss contribution
  const double ic = invc[bi];
  float2 cv = *(const float2*)(&cb[(size_t)bi * DDIM + d0]);
  double cd0 = (double)cv.x * ic, cd1 = (double)cv.y * ic;
  float2 co; co.x = (float)cd0; co.y = (float)cd1;
  const size_t ro = (size_t)n * DDIM + d0;
  *(float2*)(&out_ct[ro]) = co;
  *(float2*)(&out_ch[ro]) = co;
  *(float2*)(&out_cq[ro]) = co;

  // q one-hot row
  const int qb = tx * 4;
  float4 qv;
  qv.x = (qb + 0 == bi) ? 1.0f : 0.0f;
  qv.y = (qb + 1 == bi) ? 1.0f : 0.0f;
  qv.z = (qb + 2 == bi) ? 1.0f : 0.0f;
  qv.w = (qb + 3 == bi) ? 1.0f : 0.0f;
  *(float4*)(&out_q[(size_t)n * KCODE + qb]) = qv;

  double e0 = (double)hv.x * ih - cd0;
  double e1 = (double)hv.y * ih - cd1;
  double ls = e0 * e0 + e1 * e1;
  #pragma unroll
  for (int m = 1; m < 64; m <<= 1) ls += __shfl_xor(ls, m);
  if (lane == 0) sh[4 + wv] = ls;
  __syncthreads();
  if (tx == 0) lsum[n] = sh[4] + sh[5] + sh[6] + sh[7];
}

__global__ __launch_bounds__(256) void k_loss(const double* __restrict__ lsum,
                                              float* __restrict__ out_loss) {
  const int tx = threadIdx.x;
  double s = 0.0;
  for (int i = tx; i < NROWS; i += 256) s += lsum[i];
  #pragma unroll
  for (int m = 1; m < 64; m <<= 1) s += __shfl_xor(s, m);
  __shared__ double sh[4];
  if ((tx & 63) == 0) sh[tx >> 6] = s;
  __syncthreads();
  if (tx == 0)
    out_loss[0] = (float)(1.25 * (sh[0] + sh[1] + sh[2] + sh[3]) / ((double)NROWS * (double)DDIM));
}

extern "C" void kernel_launch(void* const* d_in, const int* in_sizes, int n_in,
                              void* d_out, int out_size, void* d_ws, size_t ws_size,
                              hipStream_t stream) {
  const float* h = (const float*)d_in[0];
  const float* cb = (const float*)d_in[1];

  float* out = (float*)d_out;
  float* out_q   = out;                    // 33554432
  float* out_ct  = out + 33554432;         // 16777216
  float* out_ch  = out + 50331648;         // 16777216
  float* out_cq  = out + 67108864;         // 16777216
  float* out_loss = out + 83886080;        // 1
  float* out_idx  = out + 83886081;        // 32768

  char* ws = (char*)d_ws;
  double* invc   = (double*)ws;                                // 8 KB
  double* pscore = (double*)(ws + 8192);                       // 1 MB
  int*    pidx   = (int*)(ws + 8192 + 1048576);                // 512 KB
  double* lsum   = (double*)(ws + 8192 + 1048576 + 524288);    // 256 KB

  k_inv_norms<<<KCODE / 4, 256, 0, stream>>>(cb, invc, KCODE);
  k_scores<<<(NROWS / 32) * 4, 256, 0, stream>>>(h, cb, invc, pscore, pidx);
  k_finalize<<<NROWS, 256, 0, stream>>>(h, cb, invc, pscore, pidx,
                                        out_q, out_ct, out_ch, out_cq, out_idx, lsum);
  k_loss<<<1, 256, 0, stream>>>(lsum, out_loss);
}

// Round 2
// 591.734 us; speedup vs baseline: 1.4955x; 1.4955x over previous
//
#include <hip/hip_runtime.h>
#include <math.h>

// VQQuantizer eval path, round 2.
// Strategy: fp32 score GEMM (2x the fp64 rate, no cvt_f64 in inner loop) with
// per-stripe top-2 + within-margin count; exact fp64 rescoring of the few
// candidates in the epilogue. Margin M = 2e-4 * ||h_row|| provably dominates
// 2x the fp32 dot error bound (512 * 2^-24 * ||h|| * ||c|| ~= 3.2e-5 * ||h||),
// so the fp64 argmax is always in the candidate set (rescan fallback if >2
// candidates land in one stripe). Staging via global_load_lds width=16
// (no ds_writes -> no staging bank conflicts); codebook pre-transposed once.

#define NROWS 32768
#define DDIM  512
#define KCODE 1024
#define SCODE 256
#define MARGIN_COEF 2e-4f

typedef __attribute__((address_space(1))) const void gvoid_t;
typedef __attribute__((address_space(3))) void svoid_t;

__device__ __forceinline__ void gl16(const void* g, void* s) {
  __builtin_amdgcn_global_load_lds((gvoid_t*)g, (svoid_t*)s, 16, 0, 0);
}

// ---------------- codebook inverse norms (fp64 + fp32 copies) ----------------
__global__ __launch_bounds__(256) void k_invc(const float* __restrict__ x,
                                              double* __restrict__ invd,
                                              float* __restrict__ invf) {
  const int lane = threadIdx.x & 63;
  const int row = blockIdx.x * 4 + (threadIdx.x >> 6);
  const float* p = x + (size_t)row * DDIM;
  float4 v0 = *(const float4*)(p + lane * 4);
  float4 v1 = *(const float4*)(p + 256 + lane * 4);
  double s = (double)v0.x * v0.x + (double)v0.y * v0.y + (double)v0.z * v0.z + (double)v0.w * v0.w
           + (double)v1.x * v1.x + (double)v1.y * v1.y + (double)v1.z * v1.z + (double)v1.w * v1.w;
  #pragma unroll
  for (int m = 1; m < 64; m <<= 1) s += __shfl_xor(s, m);
  if (lane == 0) {
    double iv = 1.0 / fmax(sqrt(s), 1e-6);
    invd[row] = iv;
    invf[row] = (float)iv;
  }
}

// ---------------- h row norms (fp64 sum, stored as f32 for margins) ----------
__global__ __launch_bounds__(256) void k_hnorm(const float* __restrict__ x,
                                               float* __restrict__ nrm) {
  const int lane = threadIdx.x & 63;
  const int row = blockIdx.x * 4 + (threadIdx.x >> 6);
  const float* p = x + (size_t)row * DDIM;
  float4 v0 = *(const float4*)(p + lane * 4);
  float4 v1 = *(const float4*)(p + 256 + lane * 4);
  double s = (double)v0.x * v0.x + (double)v0.y * v0.y + (double)v0.z * v0.z + (double)v0.w * v0.w
           + (double)v1.x * v1.x + (double)v1.y * v1.y + (double)v1.z * v1.z + (double)v1.w * v1.w;
  #pragma unroll
  for (int m = 1; m < 64; m <<= 1) s += __shfl_xor(s, m);
  if (lane == 0) nrm[row] = (float)sqrt(s);
}

// ---------------- codebook transpose: cbT[d][k] ----------------
__global__ __launch_bounds__(256) void k_tr(const float* __restrict__ cb,
                                            float* __restrict__ cbT) {
  __shared__ float t[32][33];
  const int bk = blockIdx.x & 31;  // code tile (1024/32)
  const int bd = blockIdx.x >> 5;  // d tile (512/32)
  const int x = threadIdx.x & 31;
  const int y0 = (threadIdx.x >> 5) * 4;
  #pragma unroll
  for (int i = 0; i < 4; ++i)
    t[y0 + i][x] = cb[(size_t)(bk * 32 + y0 + i) * DDIM + bd * 32 + x];
  __syncthreads();
  #pragma unroll
  for (int i = 0; i < 4; ++i)
    cbT[(size_t)(bd * 32 + y0 + i) * KCODE + bk * 32 + x] = t[x][y0 + i];
}

// ---------------- fp32 score GEMM + per-stripe top2/count ----------------
// Block 256 thr; tile 32 rows x 256 codes; wave wv owns rows wv*8..+7,
// lane owns codes c0..c0+3. A [row][dk], B [dk][code], both via global_load_lds.
__global__ __launch_bounds__(256) void k_scores(const float* __restrict__ h,
                                                const float* __restrict__ cbT,
                                                const float* __restrict__ invcf,
                                                const float* __restrict__ hnormf,
                                                float4* __restrict__ pcand,
                                                int* __restrict__ pcnt) {
  __shared__ float aN[32][32];    // 4 KB  [row][dk]
  __shared__ float bT[32][SCODE]; // 32 KB [dk][code]
  const int tx = threadIdx.x;
  const int tilec = blockIdx.x & 3;
  const int tiler = blockIdx.x >> 2;
  const int row0 = tiler * 32;
  const int col0 = tilec * SCODE;
  const int lane = tx & 63;
  const int wv = tx >> 6;
  const int r0 = wv * 8;
  const int c0 = lane * 4;

  float acc[8][4];
  #pragma unroll
  for (int r = 0; r < 8; ++r)
    #pragma unroll
    for (int c = 0; c < 4; ++c) acc[r][c] = 0.0f;

  const int arow = tx >> 3, adk = (tx & 7) * 4;
  const float* aSrc = h + (size_t)(row0 + arow) * DDIM + adk;
  float* aDst = &aN[0][0] + tx * 4;

  for (int k0 = 0; k0 < DDIM; k0 += 32) {
    __syncthreads();
    gl16(aSrc + k0, aDst);
    #pragma unroll
    for (int j = 0; j < 8; ++j) {
      const int flat4 = tx + j * 256;
      const int dk = flat4 >> 6;
      const int cc4 = flat4 & 63;
      gl16(cbT + (size_t)(k0 + dk) * KCODE + col0 + cc4 * 4, &bT[0][0] + flat4 * 4);
    }
    __syncthreads();
    #pragma unroll
    for (int kq = 0; kq < 8; ++kq) {
      float4 a[8];
      #pragma unroll
      for (int r = 0; r < 8; ++r) a[r] = *(const float4*)(&aN[r0 + r][kq * 4]);
      #pragma unroll
      for (int kl = 0; kl < 4; ++kl) {
        float4 b = *(const float4*)(&bT[kq * 4 + kl][c0]);
        #pragma unroll
        for (int r = 0; r < 8; ++r) {
          const float av = ((const float*)&a[r])[kl];
          acc[r][0] = fmaf(av, b.x, acc[r][0]);
          acc[r][1] = fmaf(av, b.y, acc[r][1]);
          acc[r][2] = fmaf(av, b.z, acc[r][2]);
          acc[r][3] = fmaf(av, b.w, acc[r][3]);
        }
      }
    }
  }

  float vinv[4];
  #pragma unroll
  for (int c = 0; c < 4; ++c) vinv[c] = invcf[col0 + c0 + c];

  #pragma unroll
  for (int r = 0; r < 8; ++r) {
    const int row = row0 + r0 + r;
    float sv[4];
    #pragma unroll
    for (int c = 0; c < 4; ++c) sv[c] = acc[r][c] * vinv[c];

    // stripe top-1 (lowest index on ties)
    float b1 = sv[0]; int i1 = col0 + c0;
    #pragma unroll
    for (int c = 1; c < 4; ++c)
      if (sv[c] > b1) { b1 = sv[c]; i1 = col0 + c0 + c; }
    float t1 = b1; int ti1 = i1;
    #pragma unroll
    for (int m = 1; m < 64; m <<= 1) {
      float os = __shfl_xor(t1, m); int oi = __shfl_xor(ti1, m);
      if (os > t1 || (os == t1 && oi < ti1)) { t1 = os; ti1 = oi; }
    }

    const float M = MARGIN_COEF * hnormf[row];
    const float thr = t1 - M;
    int cl = (sv[0] >= thr) + (sv[1] >= thr) + (sv[2] >= thr) + (sv[3] >= thr);
    #pragma unroll
    for (int m = 1; m < 64; m <<= 1) cl += __shfl_xor(cl, m);

    // stripe top-2 (best excluding ti1)
    float b2 = -3.4e38f; int i2 = 0x7fffffff;
    #pragma unroll
    for (int c = 0; c < 4; ++c) {
      const int idx = col0 + c0 + c;
      if (idx != ti1 && sv[c] > b2) { b2 = sv[c]; i2 = idx; }
    }
    #pragma unroll
    for (int m = 1; m < 64; m <<= 1) {
      float os = __shfl_xor(b2, m); int oi = __shfl_xor(i2, m);
      if (os > b2 || (os == b2 && oi < i2)) { b2 = os; i2 = oi; }
    }

    if (lane == 0) {
      pcand[row * 4 + tilec] = make_float4(t1, __int_as_float(ti1), b2, __int_as_float(i2));
      pcnt[row * 4 + tilec] = cl;
    }
  }
}

// ---------------- epilogue: fp64 candidate rescoring + outputs ----------------
__global__ __launch_bounds__(256) void k_finalize(const float* __restrict__ h,
                                                  const float* __restrict__ cb,
                                                  const double* __restrict__ invcd,
                                                  const float* __restrict__ hnormf,
                                                  const float4* __restrict__ pcand,
                                                  const int* __restrict__ pcnt,
                                                  float* __restrict__ out_q,
                                                  float* __restrict__ out_ct,
                                                  float* __restrict__ out_ch,
                                                  float* __restrict__ out_cq,
                                                  float* __restrict__ out_idx,
                                                  double* __restrict__ lsum) {
  const int n = blockIdx.x;
  const int tx = threadIdx.x;
  const int lane = tx & 63;
  const int wv = tx >> 6;
  __shared__ double shd[8];
  __shared__ double sred[4];
  __shared__ int sidx[4];
  __shared__ int scand[10];  // [0]=ncand, [1..8]=codes, [9]=rescan flags

  // fp64 row norm of h (identical structure to round-0's passing loss path)
  const int d0 = tx * 2;
  float2 hv = *(const float2*)(&h[(size_t)n * DDIM + d0]);
  double hs = (double)hv.x * hv.x + (double)hv.y * hv.y;
  #pragma unroll
  for (int m = 1; m < 64; m <<= 1) hs += __shfl_xor(hs, m);
  if (lane == 0) shd[wv] = hs;
  __syncthreads();
  const double ih = 1.0 / fmax(sqrt(shd[0] + shd[1] + shd[2] + shd[3]), 1e-6);

  // candidate set construction (scalar, thread 0)
  if (tx == 0) {
    float4 pc[4]; int ct[4];
    #pragma unroll
    for (int t = 0; t < 4; ++t) { pc[t] = pcand[n * 4 + t]; ct[t] = pcnt[n * 4 + t]; }
    float best = pc[0].x;
    #pragma unroll
    for (int t = 1; t < 4; ++t) best = fmaxf(best, pc[t].x);
    const float thr = best - MARGIN_COEF * hnormf[n];
    int nc = 0, fl = 0;
    #pragma unroll
    for (int t = 0; t < 4; ++t) {
      if (pc[t].x >= thr) scand[1 + nc++] = __float_as_int(pc[t].y);
      if (pc[t].z >= thr) {
        scand[1 + nc++] = __float_as_int(pc[t].w);
        if (ct[t] > 2) fl |= (1 << t);  // >2 in-margin codes in this stripe
      }
    }
    scand[0] = nc;
    scand[9] = fl;
  }
  __syncthreads();
  const int nc = scand[0];
  const int fl = scand[9];

  double bs = -1e300; int bi = 0x7fffffff;
  for (int ci = 0; ci < nc; ++ci) {
    const int code = scand[1 + ci];
    float2 cv = *(const float2*)(&cb[(size_t)code * DDIM + d0]);
    double p = (double)hv.x * (double)cv.x + (double)hv.y * (double)cv.y;
    #pragma unroll
    for (int m = 1; m < 64; m <<= 1) p += __shfl_xor(p, m);
    if (lane == 0) sred[wv] = p;
    __syncthreads();
    const double sc = (sred[0] + sred[1] + sred[2] + sred[3]) * invcd[code];
    if (sc > bs || (sc == bs && code < bi)) { bs = sc; bi = code; }
    __syncthreads();
  }

  if (fl) {  // pathological stripe(s): exact fp64 scan of all 256 codes
    for (int t = 0; t < 4; ++t) {
      if (!(fl & (1 << t))) continue;
      double wbs = -1e300; int wbi = 0x7fffffff;
      const float* hp = h + (size_t)n * DDIM + lane * 8;
      for (int j = 0; j < 64; ++j) {
        const int code = t * 256 + j * 4 + wv;
        const float* cp = cb + (size_t)code * DDIM + lane * 8;
        double p = 0.0;
        #pragma unroll
        for (int e = 0; e < 8; ++e) p = fma((double)hp[e], (double)cp[e], p);
        #pragma unroll
        for (int m = 1; m < 64; m <<= 1) p += __shfl_xor(p, m);
        const double sc = p * invcd[code];
        if (sc > wbs || (sc == wbs && code < wbi)) { wbs = sc; wbi = code; }
      }
      if (lane == 0) { sred[wv] = wbs; sidx[wv] = wbi; }
      __syncthreads();
      #pragma unroll
      for (int w = 0; w < 4; ++w) {
        const double sc = sred[w]; const int ii = sidx[w];
        if (sc > bs || (sc == bs && ii < bi)) { bs = sc; bi = ii; }
      }
      __syncthreads();
    }
  }

  if (tx == 0) out_idx[n] = (float)bi;

  const double ic = invcd[bi];
  float2 cv = *(const float2*)(&cb[(size_t)bi * DDIM + d0]);
  const double cd0 = (double)cv.x * ic, cd1 = (double)cv.y * ic;
  float2 co; co.x = (float)cd0; co.y = (float)cd1;
  const size_t ro = (size_t)n * DDIM + d0;
  *(float2*)(&out_ct[ro]) = co;
  *(float2*)(&out_ch[ro]) = co;
  *(float2*)(&out_cq[ro]) = co;

  const int qb = tx * 4;
  float4 qv;
  qv.x = (qb + 0 == bi) ? 1.0f : 0.0f;
  qv.y = (qb + 1 == bi) ? 1.0f : 0.0f;
  qv.z = (qb + 2 == bi) ? 1.0f : 0.0f;
  qv.w = (qb + 3 == bi) ? 1.0f : 0.0f;
  *(float4*)(&out_q[(size_t)n * KCODE + qb]) = qv;

  double e0 = (double)hv.x * ih - cd0;
  double e1 = (double)hv.y * ih - cd1;
  double ls = e0 * e0 + e1 * e1;
  #pragma unroll
  for (int m = 1; m < 64; m <<= 1) ls += __shfl_xor(ls, m);
  if (lane == 0) shd[4 + wv] = ls;
  __syncthreads();
  if (tx == 0) lsum[n] = shd[4] + shd[5] + shd[6] + shd[7];
}

__global__ __launch_bounds__(256) void k_loss(const double* __restrict__ lsum,
                                              float* __restrict__ out_loss) {
  const int tx = threadIdx.x;
  double s = 0.0;
  for (int i = tx; i < NROWS; i += 256) s += lsum[i];
  #pragma unroll
  for (int m = 1; m < 64; m <<= 1) s += __shfl_xor(s, m);
  __shared__ double sh[4];
  if ((tx & 63) == 0) sh[tx >> 6] = s;
  __syncthreads();
  if (tx == 0)
    out_loss[0] = (float)(1.25 * (sh[0] + sh[1] + sh[2] + sh[3]) / ((double)NROWS * (double)DDIM));
}

extern "C" void kernel_launch(void* const* d_in, const int* in_sizes, int n_in,
                              void* d_out, int out_size, void* d_ws, size_t ws_size,
                              hipStream_t stream) {
  const float* h = (const float*)d_in[0];
  const float* cb = (const float*)d_in[1];

  float* out = (float*)d_out;
  float* out_q    = out;
  float* out_ct   = out + 33554432;
  float* out_ch   = out + 50331648;
  float* out_cq   = out + 67108864;
  float* out_loss = out + 83886080;
  float* out_idx  = out + 83886081;

  char* ws = (char*)d_ws;
  float*  cbT    = (float*)ws;                        // 2 MB
  double* invcd  = (double*)(ws + 2097152);           // 8 KB
  float*  invcf  = (float*)(ws + 2105344);            // 4 KB
  float*  hnormf = (float*)(ws + 2109440);            // 128 KB
  float4* pcand  = (float4*)(ws + 2240512);           // 2 MB
  int*    pcnt   = (int*)(ws + 4337664);              // 512 KB
  double* lsum   = (double*)(ws + 4861952);           // 256 KB

  k_invc<<<KCODE / 4, 256, 0, stream>>>(cb, invcd, invcf);
  k_hnorm<<<NROWS / 4, 256, 0, stream>>>(h, hnormf);
  k_tr<<<512, 256, 0, stream>>>(cb, cbT);
  k_scores<<<(NROWS / 32) * 4, 256, 0, stream>>>(h, cbT, invcf, hnormf, pcand, pcnt);
  k_finalize<<<NROWS, 256, 0, stream>>>(h, cb, invcd, hnormf, pcand, pcnt,
                                        out_q, out_ct, out_ch, out_cq, out_idx, lsum);
  k_loss<<<1, 256, 0, stream>>>(lsum, out_loss);
}

// Round 4
// 402.797 us; speedup vs baseline: 2.1970x; 1.4691x over previous
//
#include <hip/hip_runtime.h>
#include <math.h>

// VQQuantizer eval, round 4 = round 3 + fixed bf16 conversion (no hip_bf16.h
// dependency; manual RNE bit-trick).
// score(n,k) = <h_n, cb_k> * invnorm(cb_k); argmax == argmin dist.
// 3-term split: a.b ~= ahi.bhi + ahi.blo + alo.bhi  (one MFMA loop, K_eff=1536)
// Error <~ 1e-4*||h||; MARGIN = 1e-3*||h||; fp64 rescoring of in-margin
// candidates (+ count-triggered 64-code stripe rescan) keeps the argmax exact
// vs the float64 numpy reference.

#define NROWS 32768
#define DDIM  512
#define KCODE 1024
#define MARGIN_COEF 1e-3f

typedef __attribute__((address_space(1))) const void gvoid_t;
typedef __attribute__((address_space(3))) void svoid_t;
typedef float f32x4 __attribute__((ext_vector_type(4)));
typedef short bf16x8 __attribute__((ext_vector_type(8)));

__device__ __forceinline__ void gl16(const void* g, void* s) {
  __builtin_amdgcn_global_load_lds((gvoid_t*)g, (svoid_t*)s, 16, 0, 0);
}
// round-to-nearest-even f32 -> bf16 (finite inputs only)
__device__ __forceinline__ unsigned short f2bf(float x) {
  unsigned u = __float_as_uint(x);
  u = u + 0x7fffu + ((u >> 16) & 1u);
  return (unsigned short)(u >> 16);
}
__device__ __forceinline__ float bf2f(unsigned short u) {
  unsigned v = (unsigned)u << 16;
  return __uint_as_float(v);
}

// ---------------- codebook inverse norms ----------------
__global__ __launch_bounds__(256) void k_invc(const float* __restrict__ x,
                                              double* __restrict__ invd,
                                              float* __restrict__ invf) {
  const int lane = threadIdx.x & 63;
  const int row = blockIdx.x * 4 + (threadIdx.x >> 6);
  const float* p = x + (size_t)row * DDIM;
  float4 v0 = *(const float4*)(p + lane * 4);
  float4 v1 = *(const float4*)(p + 256 + lane * 4);
  double s = (double)v0.x * v0.x + (double)v0.y * v0.y + (double)v0.z * v0.z + (double)v0.w * v0.w
           + (double)v1.x * v1.x + (double)v1.y * v1.y + (double)v1.z * v1.z + (double)v1.w * v1.w;
  #pragma unroll
  for (int m = 1; m < 64; m <<= 1) s += __shfl_xor(s, m);
  if (lane == 0) {
    double iv = 1.0 / fmax(sqrt(s), 1e-6);
    invd[row] = iv;
    invf[row] = (float)iv;
  }
}

// ---------------- h row norms (f32 of fp64 sum) ----------
__global__ __launch_bounds__(256) void k_hnorm(const float* __restrict__ x,
                                               float* __restrict__ nrm) {
  const int lane = threadIdx.x & 63;
  const int row = blockIdx.x * 4 + (threadIdx.x >> 6);
  const float* p = x + (size_t)row * DDIM;
  float4 v0 = *(const float4*)(p + lane * 4);
  float4 v1 = *(const float4*)(p + 256 + lane * 4);
  double s = (double)v0.x * v0.x + (double)v0.y * v0.y + (double)v0.z * v0.z + (double)v0.w * v0.w
           + (double)v1.x * v1.x + (double)v1.y * v1.y + (double)v1.z * v1.z + (double)v1.w * v1.w;
  #pragma unroll
  for (int m = 1; m < 64; m <<= 1) s += __shfl_xor(s, m);
  if (lane == 0) nrm[row] = (float)sqrt(s);
}

// ---------------- split + fragment-tile: x[16 rows x 512] -> hi/lo tiled ----
// Tiled layout, element (row,k): tile = row/16, kc = k/32,
// lane l = (row&15) | (((k>>3)&3)<<4), e = k&7.
// flat element offset = tile*8192 + kc*512 + l*8 + e.
__device__ __forceinline__ void prep_tile(const float* __restrict__ src,
                                          unsigned short* __restrict__ hi,
                                          unsigned short* __restrict__ lo,
                                          int tile) {
  const int t = threadIdx.x;
  const float4* s4 = (const float4*)(src + (size_t)tile * 16 * DDIM);
  #pragma unroll
  for (int j = 0; j < 8; ++j) {
    const int f = t + j * 256;       // float4 index in 16x512 tile
    const int rowl = f >> 7;
    const int k = (f & 127) * 4;
    float4 v = s4[f];
    const int kc = k >> 5;
    const int l = rowl | (((k >> 3) & 3) << 4);
    const size_t dst = (size_t)tile * 8192 + kc * 512 + l * 8 + (k & 7);
    ushort4 h4, l4;
    float xs[4] = {v.x, v.y, v.z, v.w};
    unsigned short hb[4], lb[4];
    #pragma unroll
    for (int c = 0; c < 4; ++c) {
      hb[c] = f2bf(xs[c]);
      lb[c] = f2bf(xs[c] - bf2f(hb[c]));
    }
    h4.x = hb[0]; h4.y = hb[1]; h4.z = hb[2]; h4.w = hb[3];
    l4.x = lb[0]; l4.y = lb[1]; l4.z = lb[2]; l4.w = lb[3];
    *(ushort4*)(hi + dst) = h4;
    *(ushort4*)(lo + dst) = l4;
  }
}

__global__ __launch_bounds__(256) void k_prepA(const float* __restrict__ h,
                                               unsigned short* __restrict__ hi,
                                               unsigned short* __restrict__ lo) {
  prep_tile(h, hi, lo, blockIdx.x);
}
__global__ __launch_bounds__(256) void k_prepB(const float* __restrict__ cb,
                                               unsigned short* __restrict__ hi,
                                               unsigned short* __restrict__ lo) {
  prep_tile(cb, hi, lo, blockIdx.x);
}

// ---------------- MFMA scorer: 128x128 tile, K_eff = 1536 -------------------
// grid 2048: pr = bid>>3 (256 row panels), pc = bid&7 (8 col panels).
// 4 waves (2x2): wave (wr,wc) -> rows wr*64+, cols wc*64+; acc 4x4 fragments.
__global__ __launch_bounds__(256) void k_mfma(const unsigned short* __restrict__ AThi,
                                              const unsigned short* __restrict__ ATlo,
                                              const unsigned short* __restrict__ BThi,
                                              const unsigned short* __restrict__ BTlo,
                                              const float* __restrict__ invcf,
                                              const float* __restrict__ hnormf,
                                              float4* __restrict__ pcand,
                                              int* __restrict__ pcnt) {
  __shared__ bf16x8 lds[1024];  // A slots 0..511, B slots 512..1023 (16 KB)
  const int tx = threadIdx.x;
  const int pr = blockIdx.x >> 3;
  const int pc = blockIdx.x & 7;
  const int lane = tx & 63;
  const int wid = tx >> 6;
  const int wr = wid >> 1, wc = wid & 1;

  f32x4 acc[4][4];
  #pragma unroll
  for (int m = 0; m < 4; ++m)
    #pragma unroll
    for (int n = 0; n < 4; ++n)
      acc[m][n] = (f32x4)(0.0f);

  // staging source offsets (elements), kc term added in-loop
  const int sA = tx >> 6;       // first subtile this thread stages (A and B)
  const int li = tx & 63;
  const size_t aoff0 = (size_t)(pr * 8 + sA) * 8192 + li * 8;
  const size_t aoff1 = (size_t)(pr * 8 + sA + 4) * 8192 + li * 8;
  const size_t boff0 = (size_t)(pc * 8 + sA) * 8192 + li * 8;
  const size_t boff1 = (size_t)(pc * 8 + sA + 4) * 8192 + li * 8;

  for (int ks = 0; ks < 48; ++ks) {
    const int kco = (ks & 15) * 512;
    const unsigned short* Asrc = (ks < 32) ? AThi : ATlo;
    const unsigned short* Bsrc = (ks < 16) ? BThi : ((ks < 32) ? BTlo : BThi);
    __syncthreads();  // previous iteration's readers done
    gl16(Asrc + aoff0 + kco, &lds[tx]);
    gl16(Asrc + aoff1 + kco, &lds[tx + 256]);
    gl16(Bsrc + boff0 + kco, &lds[512 + tx]);
    gl16(Bsrc + boff1 + kco, &lds[512 + tx + 256]);
    __syncthreads();  // loads landed (compiler drains vmcnt before barrier)
    bf16x8 af[4], bfr[4];
    #pragma unroll
    for (int m = 0; m < 4; ++m) af[m] = lds[(wr * 4 + m) * 64 + lane];
    #pragma unroll
    for (int n = 0; n < 4; ++n) bfr[n] = lds[512 + (wc * 4 + n) * 64 + lane];
    #pragma unroll
    for (int m = 0; m < 4; ++m)
      #pragma unroll
      for (int n = 0; n < 4; ++n)
        acc[m][n] = __builtin_amdgcn_mfma_f32_16x16x32_bf16(af[m], bfr[n], acc[m][n], 0, 0, 0);
  }

  // ---- epilogue: per-row top1/top2/cnt over this wave's 64 cols ----
  const int rowbase = pr * 128 + wr * 64;
  const int colbase = pc * 128 + wc * 64;
  const int q = lane >> 4;
  const int c16 = lane & 15;

  float invn[4];
  #pragma unroll
  for (int n = 0; n < 4; ++n) invn[n] = invcf[colbase + n * 16 + c16];

  #pragma unroll
  for (int m = 0; m < 4; ++m) {
    #pragma unroll
    for (int r = 0; r < 4; ++r) {
      const int row = rowbase + m * 16 + q * 4 + r;
      float sv[4];
      #pragma unroll
      for (int n = 0; n < 4; ++n) sv[n] = acc[m][n][r] * invn[n];

      // top1 (lowest index on ties)
      float t1 = sv[0]; int i1 = colbase + c16;
      #pragma unroll
      for (int n = 1; n < 4; ++n) {
        const int idx = colbase + n * 16 + c16;
        if (sv[n] > t1) { t1 = sv[n]; i1 = idx; }
      }
      #pragma unroll
      for (int msk = 1; msk < 16; msk <<= 1) {
        float os = __shfl_xor(t1, msk); int oi = __shfl_xor(i1, msk);
        if (os > t1 || (os == t1 && oi < i1)) { t1 = os; i1 = oi; }
      }

      const float thr = t1 - MARGIN_COEF * hnormf[row];
      int cnt = 0;
      float t2 = -3.4e38f; int i2 = 0x7fffffff;
      #pragma unroll
      for (int n = 0; n < 4; ++n) {
        const int idx = colbase + n * 16 + c16;
        cnt += (sv[n] >= thr);
        if (idx != i1 && sv[n] > t2) { t2 = sv[n]; i2 = idx; }
      }
      #pragma unroll
      for (int msk = 1; msk < 16; msk <<= 1) {
        cnt += __shfl_xor(cnt, msk);
        float os = __shfl_xor(t2, msk); int oi = __shfl_xor(i2, msk);
        if (os > t2 || (os == t2 && oi < i2)) { t2 = os; i2 = oi; }
      }

      if (c16 == 0) {
        const int st = pc * 2 + wc;   // 16 stripes of 64 cols
        pcand[(size_t)row * 16 + st] = make_float4(t1, __int_as_float(i1), t2, __int_as_float(i2));
        pcnt[(size_t)row * 16 + st] = cnt;
      }
    }
  }
}

// ---------------- epilogue: fp64 rescoring + outputs ----------------
__global__ __launch_bounds__(256) void k_finalize(const float* __restrict__ h,
                                                  const float* __restrict__ cb,
                                                  const double* __restrict__ invcd,
                                                  const float* __restrict__ hnormf,
                                                  const float4* __restrict__ pcand,
                                                  const int* __restrict__ pcnt,
                                                  float* __restrict__ out_q,
                                                  float* __restrict__ out_ct,
                                                  float* __restrict__ out_ch,
                                                  float* __restrict__ out_cq,
                                                  float* __restrict__ out_idx,
                                                  double* __restrict__ lsum) {
  const int n = blockIdx.x;
  const int tx = threadIdx.x;
  const int lane = tx & 63;
  const int wv = tx >> 6;
  __shared__ double shd[8];
  __shared__ double sred[4];
  __shared__ int sidx[4];
  __shared__ float4 spc[16];
  __shared__ int sct[16];
  __shared__ int scand[34];  // [0]=nc, [1..32]=codes, [33]=rescan flags

  const int d0 = tx * 2;
  float2 hv = *(const float2*)(&h[(size_t)n * DDIM + d0]);
  double hs = (double)hv.x * hv.x + (double)hv.y * hv.y;
  #pragma unroll
  for (int m = 1; m < 64; m <<= 1) hs += __shfl_xor(hs, m);
  if (lane == 0) shd[wv] = hs;
  if (tx < 16) { spc[tx] = pcand[(size_t)n * 16 + tx]; sct[tx] = pcnt[(size_t)n * 16 + tx]; }
  __syncthreads();
  const double ih = 1.0 / fmax(sqrt(shd[0] + shd[1] + shd[2] + shd[3]), 1e-6);

  if (tx == 0) {
    float best = spc[0].x;
    #pragma unroll
    for (int t = 1; t < 16; ++t) best = fmaxf(best, spc[t].x);
    const float thr = best - MARGIN_COEF * hnormf[n];
    int nc = 0, fl = 0;
    #pragma unroll
    for (int t = 0; t < 16; ++t) {
      if (spc[t].x >= thr) scand[1 + nc++] = __float_as_int(spc[t].y);
      if (spc[t].z >= thr) {
        scand[1 + nc++] = __float_as_int(spc[t].w);
        if (sct[t] > 2) fl |= (1 << t);
      }
    }
    scand[0] = nc;
    scand[33] = fl;
  }
  __syncthreads();
  const int nc = scand[0];
  const int fl = scand[33];

  double bs = -1e300; int bi = 0x7fffffff;
  for (int ci = 0; ci < nc; ++ci) {
    const int code = scand[1 + ci];
    float2 cv = *(const float2*)(&cb[(size_t)code * DDIM + d0]);
    double p = (double)hv.x * (double)cv.x + (double)hv.y * (double)cv.y;
    #pragma unroll
    for (int m = 1; m < 64; m <<= 1) p += __shfl_xor(p, m);
    if (lane == 0) sred[wv] = p;
    __syncthreads();
    const double sc = (sred[0] + sred[1] + sred[2] + sred[3]) * invcd[code];
    if (sc > bs || (sc == bs && code < bi)) { bs = sc; bi = code; }
    __syncthreads();
  }

  if (fl) {  // pathological stripes: exact fp64 scan of 64 codes each
    for (int t = 0; t < 16; ++t) {
      if (!(fl & (1 << t))) continue;
      double wbs = -1e300; int wbi = 0x7fffffff;
      const float* hp = h + (size_t)n * DDIM + lane * 8;
      for (int j = 0; j < 16; ++j) {
        const int code = t * 64 + j * 4 + wv;
        const float* cp = cb + (size_t)code * DDIM + lane * 8;
        double p = 0.0;
        #pragma unroll
        for (int e = 0; e < 8; ++e) p = fma((double)hp[e], (double)cp[e], p);
        #pragma unroll
        for (int m = 1; m < 64; m <<= 1) p += __shfl_xor(p, m);
        const double sc = p * invcd[code];
        if (sc > wbs || (sc == wbs && code < wbi)) { wbs = sc; wbi = code; }
      }
      if (lane == 0) { sred[wv] = wbs; sidx[wv] = wbi; }
      __syncthreads();
      #pragma unroll
      for (int w = 0; w < 4; ++w) {
        const double sc = sred[w]; const int ii = sidx[w];
        if (sc > bs || (sc == bs && ii < bi)) { bs = sc; bi = ii; }
      }
      __syncthreads();
    }
  }

  if (tx == 0) out_idx[n] = (float)bi;

  const double ic = invcd[bi];
  float2 cv = *(const float2*)(&cb[(size_t)bi * DDIM + d0]);
  const double cd0 = (double)cv.x * ic, cd1 = (double)cv.y * ic;
  float2 co; co.x = (float)cd0; co.y = (float)cd1;
  const size_t ro = (size_t)n * DDIM + d0;
  *(float2*)(&out_ct[ro]) = co;
  *(float2*)(&out_ch[ro]) = co;
  *(float2*)(&out_cq[ro]) = co;

  const int qb = tx * 4;
  float4 qv;
  qv.x = (qb + 0 == bi) ? 1.0f : 0.0f;
  qv.y = (qb + 1 == bi) ? 1.0f : 0.0f;
  qv.z = (qb + 2 == bi) ? 1.0f : 0.0f;
  qv.w = (qb + 3 == bi) ? 1.0f : 0.0f;
  *(float4*)(&out_q[(size_t)n * KCODE + qb]) = qv;

  double e0 = (double)hv.x * ih - cd0;
  double e1 = (double)hv.y * ih - cd1;
  double ls = e0 * e0 + e1 * e1;
  #pragma unroll
  for (int m = 1; m < 64; m <<= 1) ls += __shfl_xor(ls, m);
  if (lane == 0) shd[4 + wv] = ls;
  __syncthreads();
  if (tx == 0) lsum[n] = shd[4] + shd[5] + shd[6] + shd[7];
}

__global__ __launch_bounds__(256) void k_loss(const double* __restrict__ lsum,
                                              float* __restrict__ out_loss) {
  const int tx = threadIdx.x;
  double s = 0.0;
  for (int i = tx; i < NROWS; i += 256) s += lsum[i];
  #pragma unroll
  for (int m = 1; m < 64; m <<= 1) s += __shfl_xor(s, m);
  __shared__ double sh[4];
  if ((tx & 63) == 0) sh[tx >> 6] = s;
  __syncthreads();
  if (tx == 0)
    out_loss[0] = (float)(1.25 * (sh[0] + sh[1] + sh[2] + sh[3]) / ((double)NROWS * (double)DDIM));
}

extern "C" void kernel_launch(void* const* d_in, const int* in_sizes, int n_in,
                              void* d_out, int out_size, void* d_ws, size_t ws_size,
                              hipStream_t stream) {
  const float* h = (const float*)d_in[0];
  const float* cb = (const float*)d_in[1];

  float* out = (float*)d_out;
  float* out_q    = out;
  float* out_ct   = out + 33554432;
  float* out_ch   = out + 50331648;
  float* out_cq   = out + 67108864;
  float* out_loss = out + 83886080;
  float* out_idx  = out + 83886081;

  char* ws = (char*)d_ws;
  unsigned short* AThi = (unsigned short*)(ws);                    // 32 MB
  unsigned short* ATlo = (unsigned short*)(ws + 33554432);         // 32 MB
  unsigned short* BThi = (unsigned short*)(ws + 67108864);         // 1 MB
  unsigned short* BTlo = (unsigned short*)(ws + 68157440);         // 1 MB
  double* invcd  = (double*)(ws + 69206016);                       // 8 KB
  float*  invcf  = (float*)(ws + 69214208);                        // 4 KB
  float*  hnormf = (float*)(ws + 69218304);                        // 128 KB
  float4* pcand  = (float4*)(ws + 69349376);                       // 8 MB
  int*    pcnt   = (int*)(ws + 77737984);                          // 2 MB
  double* lsum   = (double*)(ws + 79835136);                       // 256 KB

  k_invc<<<KCODE / 4, 256, 0, stream>>>(cb, invcd, invcf);
  k_hnorm<<<NROWS / 4, 256, 0, stream>>>(h, hnormf);
  k_prepA<<<NROWS / 16, 256, 0, stream>>>(h, AThi, ATlo);
  k_prepB<<<KCODE / 16, 256, 0, stream>>>(cb, BThi, BTlo);
  k_mfma<<<2048, 256, 0, stream>>>(AThi, ATlo, BThi, BTlo, invcf, hnormf, pcand, pcnt);
  k_finalize<<<NROWS, 256, 0, stream>>>(h, cb, invcd, hnormf, pcand, pcnt,
                                        out_q, out_ct, out_ch, out_cq, out_idx, lsum);
  k_loss<<<1, 256, 0, stream>>>(lsum, out_loss);
}

// Round 5
// 353.809 us; speedup vs baseline: 2.5011x; 1.1385x over previous
//
#include <hip/hip_runtime.h>
#include <math.h>

// VQQuantizer eval, round 5.
// Same exactness machinery as round 4 (bf16 3-term split MFMA scorer, margin
// 1e-3*||h||, fp64 candidate rescoring + stripe rescan fallback).
// k_mfma restructured: 16 K-chunks, stage {Ahi,Alo,Bhi,Blo} together (32 KB),
// 48 MFMA/wave per barrier, double-buffered LDS w/ prefetch (one barrier per
// chunk), and an XCD-locality block swizzle so same-A blocks share an L2.

#define NROWS 32768
#define DDIM  512
#define KCODE 1024
#define MARGIN_COEF 1e-3f

typedef __attribute__((address_space(1))) const void gvoid_t;
typedef __attribute__((address_space(3))) void svoid_t;
typedef float f32x4 __attribute__((ext_vector_type(4)));
typedef short bf16x8 __attribute__((ext_vector_type(8)));

__device__ __forceinline__ void gl16(const void* g, void* s) {
  __builtin_amdgcn_global_load_lds((gvoid_t*)g, (svoid_t*)s, 16, 0, 0);
}
// round-to-nearest-even f32 -> bf16 (finite inputs only)
__device__ __forceinline__ unsigned short f2bf(float x) {
  unsigned u = __float_as_uint(x);
  u = u + 0x7fffu + ((u >> 16) & 1u);
  return (unsigned short)(u >> 16);
}
__device__ __forceinline__ float bf2f(unsigned short u) {
  unsigned v = (unsigned)u << 16;
  return __uint_as_float(v);
}

// ---------------- codebook inverse norms ----------------
__global__ __launch_bounds__(256) void k_invc(const float* __restrict__ x,
                                              double* __restrict__ invd,
                                              float* __restrict__ invf) {
  const int lane = threadIdx.x & 63;
  const int row = blockIdx.x * 4 + (threadIdx.x >> 6);
  const float* p = x + (size_t)row * DDIM;
  float4 v0 = *(const float4*)(p + lane * 4);
  float4 v1 = *(const float4*)(p + 256 + lane * 4);
  double s = (double)v0.x * v0.x + (double)v0.y * v0.y + (double)v0.z * v0.z + (double)v0.w * v0.w
           + (double)v1.x * v1.x + (double)v1.y * v1.y + (double)v1.z * v1.z + (double)v1.w * v1.w;
  #pragma unroll
  for (int m = 1; m < 64; m <<= 1) s += __shfl_xor(s, m);
  if (lane == 0) {
    double iv = 1.0 / fmax(sqrt(s), 1e-6);
    invd[row] = iv;
    invf[row] = (float)iv;
  }
}

// ---------------- h row norms (f32 of fp64 sum) ----------
__global__ __launch_bounds__(256) void k_hnorm(const float* __restrict__ x,
                                               float* __restrict__ nrm) {
  const int lane = threadIdx.x & 63;
  const int row = blockIdx.x * 4 + (threadIdx.x >> 6);
  const float* p = x + (size_t)row * DDIM;
  float4 v0 = *(const float4*)(p + lane * 4);
  float4 v1 = *(const float4*)(p + 256 + lane * 4);
  double s = (double)v0.x * v0.x + (double)v0.y * v0.y + (double)v0.z * v0.z + (double)v0.w * v0.w
           + (double)v1.x * v1.x + (double)v1.y * v1.y + (double)v1.z * v1.z + (double)v1.w * v1.w;
  #pragma unroll
  for (int m = 1; m < 64; m <<= 1) s += __shfl_xor(s, m);
  if (lane == 0) nrm[row] = (float)sqrt(s);
}

// ---------------- split + fragment-tile: x[16 rows x 512] -> hi/lo tiled ----
// Tiled layout, element (row,k): tile = row/16, kc = k/32,
// lane l = (row&15) | (((k>>3)&3)<<4), e = k&7.
// flat element offset = tile*8192 + kc*512 + l*8 + e.
__device__ __forceinline__ void prep_tile(const float* __restrict__ src,
                                          unsigned short* __restrict__ hi,
                                          unsigned short* __restrict__ lo,
                                          int tile) {
  const int t = threadIdx.x;
  const float4* s4 = (const float4*)(src + (size_t)tile * 16 * DDIM);
  #pragma unroll
  for (int j = 0; j < 8; ++j) {
    const int f = t + j * 256;       // float4 index in 16x512 tile
    const int rowl = f >> 7;
    const int k = (f & 127) * 4;
    float4 v = s4[f];
    const int kc = k >> 5;
    const int l = rowl | (((k >> 3) & 3) << 4);
    const size_t dst = (size_t)tile * 8192 + kc * 512 + l * 8 + (k & 7);
    ushort4 h4, l4;
    float xs[4] = {v.x, v.y, v.z, v.w};
    unsigned short hb[4], lb[4];
    #pragma unroll
    for (int c = 0; c < 4; ++c) {
      hb[c] = f2bf(xs[c]);
      lb[c] = f2bf(xs[c] - bf2f(hb[c]));
    }
    h4.x = hb[0]; h4.y = hb[1]; h4.z = hb[2]; h4.w = hb[3];
    l4.x = lb[0]; l4.y = lb[1]; l4.z = lb[2]; l4.w = lb[3];
    *(ushort4*)(hi + dst) = h4;
    *(ushort4*)(lo + dst) = l4;
  }
}

__global__ __launch_bounds__(256) void k_prepA(const float* __restrict__ h,
                                               unsigned short* __restrict__ hi,
                                               unsigned short* __restrict__ lo) {
  prep_tile(h, hi, lo, blockIdx.x);
}
__global__ __launch_bounds__(256) void k_prepB(const float* __restrict__ cb,
                                               unsigned short* __restrict__ hi,
                                               unsigned short* __restrict__ lo) {
  prep_tile(cb, hi, lo, blockIdx.x);
}

// ---------------- MFMA scorer: 128x128 tile, 3-term split ------------------
// Block swizzle: pr=(bid>>6)*8+(bid&7), pc=(bid>>3)&7  (bijective over 2048).
// All 8 pc-blocks of a pr share bid%8 (same XCD) and are consecutive in that
// XCD's dispatch order -> A panel (256 KB) stays in its 4MB L2.
// Per K-chunk (32): stage Ahi/Alo/Bhi/Blo (32 KB), 48 MFMA/wave, 1 barrier.
__global__ __launch_bounds__(256) void k_mfma(const unsigned short* __restrict__ AThi,
                                              const unsigned short* __restrict__ ATlo,
                                              const unsigned short* __restrict__ BThi,
                                              const unsigned short* __restrict__ BTlo,
                                              const float* __restrict__ invcf,
                                              const float* __restrict__ hnormf,
                                              float4* __restrict__ pcand,
                                              int* __restrict__ pcnt) {
  __shared__ bf16x8 lds[4096];  // 2 bufs x {Ahi,Alo,Bhi,Blo} x 512 slots (64 KB)
  const int tx = threadIdx.x;
  const int bid = blockIdx.x;
  const int pr = (bid >> 6) * 8 + (bid & 7);
  const int pc = (bid >> 3) & 7;
  const int lane = tx & 63;
  const int wid = tx >> 6;
  const int wr = wid >> 1, wc = wid & 1;

  f32x4 acc[4][4];
  #pragma unroll
  for (int m = 0; m < 4; ++m)
    #pragma unroll
    for (int n = 0; n < 4; ++n)
      acc[m][n] = (f32x4)(0.0f);

  // staging source offsets (elements): thread stages subtile tx>>6 and +4,
  // lane li = tx&63 at element li*8 (16 B), kc term added in-loop.
  const int sA = tx >> 6;
  const int li = tx & 63;
  const size_t aoff0 = (size_t)(pr * 8 + sA) * 8192 + li * 8;
  const size_t aoff1 = (size_t)(pr * 8 + sA + 4) * 8192 + li * 8;
  const size_t boff0 = (size_t)(pc * 8 + sA) * 8192 + li * 8;
  const size_t boff1 = (size_t)(pc * 8 + sA + 4) * 8192 + li * 8;

  // prologue: stage chunk 0 into buf 0
  {
    bf16x8* base = &lds[0];
    gl16(AThi + aoff0, base + tx);
    gl16(AThi + aoff1, base + 256 + tx);
    gl16(ATlo + aoff0, base + 512 + tx);
    gl16(ATlo + aoff1, base + 768 + tx);
    gl16(BThi + boff0, base + 1024 + tx);
    gl16(BThi + boff1, base + 1280 + tx);
    gl16(BTlo + boff0, base + 1536 + tx);
    gl16(BTlo + boff1, base + 1792 + tx);
  }
  __syncthreads();

  int cur = 0;
  for (int kc = 0; kc < 16; ++kc) {
    if (kc < 15) {  // prefetch next chunk into other buffer
      const int kco = (kc + 1) * 512;
      bf16x8* base = &lds[(cur ^ 1) * 2048];
      gl16(AThi + aoff0 + kco, base + tx);
      gl16(AThi + aoff1 + kco, base + 256 + tx);
      gl16(ATlo + aoff0 + kco, base + 512 + tx);
      gl16(ATlo + aoff1 + kco, base + 768 + tx);
      gl16(BThi + boff0 + kco, base + 1024 + tx);
      gl16(BThi + boff1 + kco, base + 1280 + tx);
      gl16(BTlo + boff0 + kco, base + 1536 + tx);
      gl16(BTlo + boff1 + kco, base + 1792 + tx);
    }
    const bf16x8* L = &lds[cur * 2048];
    bf16x8 ah[4], al[4], bh[4], bl[4];
    #pragma unroll
    for (int m = 0; m < 4; ++m) {
      ah[m] = L[(wr * 4 + m) * 64 + lane];
      al[m] = L[512 + (wr * 4 + m) * 64 + lane];
    }
    #pragma unroll
    for (int n = 0; n < 4; ++n) {
      bh[n] = L[1024 + (wc * 4 + n) * 64 + lane];
      bl[n] = L[1536 + (wc * 4 + n) * 64 + lane];
    }
    #pragma unroll
    for (int m = 0; m < 4; ++m)
      #pragma unroll
      for (int n = 0; n < 4; ++n)
        acc[m][n] = __builtin_amdgcn_mfma_f32_16x16x32_bf16(ah[m], bh[n], acc[m][n], 0, 0, 0);
    #pragma unroll
    for (int m = 0; m < 4; ++m)
      #pragma unroll
      for (int n = 0; n < 4; ++n)
        acc[m][n] = __builtin_amdgcn_mfma_f32_16x16x32_bf16(ah[m], bl[n], acc[m][n], 0, 0, 0);
    #pragma unroll
    for (int m = 0; m < 4; ++m)
      #pragma unroll
      for (int n = 0; n < 4; ++n)
        acc[m][n] = __builtin_amdgcn_mfma_f32_16x16x32_bf16(al[m], bh[n], acc[m][n], 0, 0, 0);
    __syncthreads();  // drains vmcnt (prefetch landed) + all waves done reading
    cur ^= 1;
  }

  // ---- epilogue: per-row top1/top2/cnt over this wave's 64 cols ----
  const int rowbase = pr * 128 + wr * 64;
  const int colbase = pc * 128 + wc * 64;
  const int q = lane >> 4;
  const int c16 = lane & 15;

  float invn[4];
  #pragma unroll
  for (int n = 0; n < 4; ++n) invn[n] = invcf[colbase + n * 16 + c16];

  #pragma unroll
  for (int m = 0; m < 4; ++m) {
    #pragma unroll
    for (int r = 0; r < 4; ++r) {
      const int row = rowbase + m * 16 + q * 4 + r;
      float sv[4];
      #pragma unroll
      for (int n = 0; n < 4; ++n) sv[n] = acc[m][n][r] * invn[n];

      // top1 (lowest index on ties)
      float t1 = sv[0]; int i1 = colbase + c16;
      #pragma unroll
      for (int n = 1; n < 4; ++n) {
        const int idx = colbase + n * 16 + c16;
        if (sv[n] > t1) { t1 = sv[n]; i1 = idx; }
      }
      #pragma unroll
      for (int msk = 1; msk < 16; msk <<= 1) {
        float os = __shfl_xor(t1, msk); int oi = __shfl_xor(i1, msk);
        if (os > t1 || (os == t1 && oi < i1)) { t1 = os; i1 = oi; }
      }

      const float thr = t1 - MARGIN_COEF * hnormf[row];
      int cnt = 0;
      float t2 = -3.4e38f; int i2 = 0x7fffffff;
      #pragma unroll
      for (int n = 0; n < 4; ++n) {
        const int idx = colbase + n * 16 + c16;
        cnt += (sv[n] >= thr);
        if (idx != i1 && sv[n] > t2) { t2 = sv[n]; i2 = idx; }
      }
      #pragma unroll
      for (int msk = 1; msk < 16; msk <<= 1) {
        cnt += __shfl_xor(cnt, msk);
        float os = __shfl_xor(t2, msk); int oi = __shfl_xor(i2, msk);
        if (os > t2 || (os == t2 && oi < i2)) { t2 = os; i2 = oi; }
      }

      if (c16 == 0) {
        const int st = pc * 2 + wc;   // 16 stripes of 64 cols
        pcand[(size_t)row * 16 + st] = make_float4(t1, __int_as_float(i1), t2, __int_as_float(i2));
        pcnt[(size_t)row * 16 + st] = cnt;
      }
    }
  }
}

// ---------------- epilogue: fp64 rescoring + outputs ----------------
__global__ __launch_bounds__(256) void k_finalize(const float* __restrict__ h,
                                                  const float* __restrict__ cb,
                                                  const double* __restrict__ invcd,
                                                  const float* __restrict__ hnormf,
                                                  const float4* __restrict__ pcand,
                                                  const int* __restrict__ pcnt,
                                                  float* __restrict__ out_q,
                                                  float* __restrict__ out_ct,
                                                  float* __restrict__ out_ch,
                                                  float* __restrict__ out_cq,
                                                  float* __restrict__ out_idx,
                                                  double* __restrict__ lsum) {
  const int n = blockIdx.x;
  const int tx = threadIdx.x;
  const int lane = tx & 63;
  const int wv = tx >> 6;
  __shared__ double shd[8];
  __shared__ double sred[4];
  __shared__ int sidx[4];
  __shared__ float4 spc[16];
  __shared__ int sct[16];
  __shared__ int scand[34];  // [0]=nc, [1..32]=codes, [33]=rescan flags

  const int d0 = tx * 2;
  float2 hv = *(const float2*)(&h[(size_t)n * DDIM + d0]);
  double hs = (double)hv.x * hv.x + (double)hv.y * hv.y;
  #pragma unroll
  for (int m = 1; m < 64; m <<= 1) hs += __shfl_xor(hs, m);
  if (lane == 0) shd[wv] = hs;
  if (tx < 16) { spc[tx] = pcand[(size_t)n * 16 + tx]; sct[tx] = pcnt[(size_t)n * 16 + tx]; }
  __syncthreads();
  const double ih = 1.0 / fmax(sqrt(shd[0] + shd[1] + shd[2] + shd[3]), 1e-6);

  if (tx == 0) {
    float best = spc[0].x;
    #pragma unroll
    for (int t = 1; t < 16; ++t) best = fmaxf(best, spc[t].x);
    const float thr = best - MARGIN_COEF * hnormf[n];
    int nc = 0, fl = 0;
    #pragma unroll
    for (int t = 0; t < 16; ++t) {
      if (spc[t].x >= thr) scand[1 + nc++] = __float_as_int(spc[t].y);
      if (spc[t].z >= thr) {
        scand[1 + nc++] = __float_as_int(spc[t].w);
        if (sct[t] > 2) fl |= (1 << t);
      }
    }
    scand[0] = nc;
    scand[33] = fl;
  }
  __syncthreads();
  const int nc = scand[0];
  const int fl = scand[33];

  double bs = -1e300; int bi = 0x7fffffff;
  for (int ci = 0; ci < nc; ++ci) {
    const int code = scand[1 + ci];
    float2 cv = *(const float2*)(&cb[(size_t)code * DDIM + d0]);
    double p = (double)hv.x * (double)cv.x + (double)hv.y * (double)cv.y;
    #pragma unroll
    for (int m = 1; m < 64; m <<= 1) p += __shfl_xor(p, m);
    if (lane == 0) sred[wv] = p;
    __syncthreads();
    const double sc = (sred[0] + sred[1] + sred[2] + sred[3]) * invcd[code];
    if (sc > bs || (sc == bs && code < bi)) { bs = sc; bi = code; }
    __syncthreads();
  }

  if (fl) {  // pathological stripes: exact fp64 scan of 64 codes each
    for (int t = 0; t < 16; ++t) {
      if (!(fl & (1 << t))) continue;
      double wbs = -1e300; int wbi = 0x7fffffff;
      const float* hp = h + (size_t)n * DDIM + lane * 8;
      for (int j = 0; j < 16; ++j) {
        const int code = t * 64 + j * 4 + wv;
        const float* cp = cb + (size_t)code * DDIM + lane * 8;
        double p = 0.0;
        #pragma unroll
        for (int e = 0; e < 8; ++e) p = fma((double)hp[e], (double)cp[e], p);
        #pragma unroll
        for (int m = 1; m < 64; m <<= 1) p += __shfl_xor(p, m);
        const double sc = p * invcd[code];
        if (sc > wbs || (sc == wbs && code < wbi)) { wbs = sc; wbi = code; }
      }
      if (lane == 0) { sred[wv] = wbs; sidx[wv] = wbi; }
      __syncthreads();
      #pragma unroll
      for (int w = 0; w < 4; ++w) {
        const double sc = sred[w]; const int ii = sidx[w];
        if (sc > bs || (sc == bs && ii < bi)) { bs = sc; bi = ii; }
      }
      __syncthreads();
    }
  }

  if (tx == 0) out_idx[n] = (float)bi;

  const double ic = invcd[bi];
  float2 cv = *(const float2*)(&cb[(size_t)bi * DDIM + d0]);
  const double cd0 = (double)cv.x * ic, cd1 = (double)cv.y * ic;
  float2 co; co.x = (float)cd0; co.y = (float)cd1;
  const size_t ro = (size_t)n * DDIM + d0;
  *(float2*)(&out_ct[ro]) = co;
  *(float2*)(&out_ch[ro]) = co;
  *(float2*)(&out_cq[ro]) = co;

  const int qb = tx * 4;
  float4 qv;
  qv.x = (qb + 0 == bi) ? 1.0f : 0.0f;
  qv.y = (qb + 1 == bi) ? 1.0f : 0.0f;
  qv.z = (qb + 2 == bi) ? 1.0f : 0.0f;
  qv.w = (qb + 3 == bi) ? 1.0f : 0.0f;
  *(float4*)(&out_q[(size_t)n * KCODE + qb]) = qv;

  double e0 = (double)hv.x * ih - cd0;
  double e1 = (double)hv.y * ih - cd1;
  double ls = e0 * e0 + e1 * e1;
  #pragma unroll
  for (int m = 1; m < 64; m <<= 1) ls += __shfl_xor(ls, m);
  if (lane == 0) shd[4 + wv] = ls;
  __syncthreads();
  if (tx == 0) lsum[n] = shd[4] + shd[5] + shd[6] + shd[7];
}

__global__ __launch_bounds__(256) void k_loss(const double* __restrict__ lsum,
                                              float* __restrict__ out_loss) {
  const int tx = threadIdx.x;
  double s = 0.0;
  for (int i = tx; i < NROWS; i += 256) s += lsum[i];
  #pragma unroll
  for (int m = 1; m < 64; m <<= 1) s += __shfl_xor(s, m);
  __shared__ double sh[4];
  if ((tx & 63) == 0) sh[tx >> 6] = s;
  __syncthreads();
  if (tx == 0)
    out_loss[0] = (float)(1.25 * (sh[0] + sh[1] + sh[2] + sh[3]) / ((double)NROWS * (double)DDIM));
}

extern "C" void kernel_launch(void* const* d_in, const int* in_sizes, int n_in,
                              void* d_out, int out_size, void* d_ws, size_t ws_size,
                              hipStream_t stream) {
  const float* h = (const float*)d_in[0];
  const float* cb = (const float*)d_in[1];

  float* out = (float*)d_out;
  float* out_q    = out;
  float* out_ct   = out + 33554432;
  float* out_ch   = out + 50331648;
  float* out_cq   = out + 67108864;
  float* out_loss = out + 83886080;
  float* out_idx  = out + 83886081;

  char* ws = (char*)d_ws;
  unsigned short* AThi = (unsigned short*)(ws);                    // 32 MB
  unsigned short* ATlo = (unsigned short*)(ws + 33554432);         // 32 MB
  unsigned short* BThi = (unsigned short*)(ws + 67108864);         // 1 MB
  unsigned short* BTlo = (unsigned short*)(ws + 68157440);         // 1 MB
  double* invcd  = (double*)(ws + 69206016);                       // 8 KB
  float*  invcf  = (float*)(ws + 69214208);                        // 4 KB
  float*  hnormf = (float*)(ws + 69218304);                        // 128 KB
  float4* pcand  = (float4*)(ws + 69349376);                       // 8 MB
  int*    pcnt   = (int*)(ws + 77737984);                          // 2 MB
  double* lsum   = (double*)(ws + 79835136);                       // 256 KB

  k_invc<<<KCODE / 4, 256, 0, stream>>>(cb, invcd, invcf);
  k_hnorm<<<NROWS / 4, 256, 0, stream>>>(h, hnormf);
  k_prepA<<<NROWS / 16, 256, 0, stream>>>(h, AThi, ATlo);
  k_prepB<<<KCODE / 16, 256, 0, stream>>>(cb, BThi, BTlo);
  k_mfma<<<2048, 256, 0, stream>>>(AThi, ATlo, BThi, BTlo, invcf, hnormf, pcand, pcnt);
  k_finalize<<<NROWS, 256, 0, stream>>>(h, cb, invcd, hnormf, pcand, pcnt,
                                        out_q, out_ct, out_ch, out_cq, out_idx, lsum);
  k_loss<<<1, 256, 0, stream>>>(lsum, out_loss);
}

// Round 6
// 351.207 us; speedup vs baseline: 2.5197x; 1.0074x over previous
//
#include <hip/hip_runtime.h>
#include <math.h>

// VQQuantizer eval, round 6: hi-only bf16 MFMA scorer (margin widened to
// 0.017*||h||, provably >= 2x the hi-only approx error 0.0079*||h||), 256x256
// tile / BK=32 double-buffered (staged bytes 1.5 GB -> 128 MB), prep fused
// with h-norm computation. Exactness: fp64 rescoring of all in-margin
// candidates + cnt-triggered 64-code stripe fp64 rescan (unchanged, airtight).

#define NROWS 32768
#define DDIM  512
#define KCODE 1024
#define MARGIN_COEF 0.017f

typedef __attribute__((address_space(1))) const void gvoid_t;
typedef __attribute__((address_space(3))) void svoid_t;
typedef float f32x4 __attribute__((ext_vector_type(4)));
typedef short bf16x8 __attribute__((ext_vector_type(8)));

__device__ __forceinline__ void gl16(const void* g, void* s) {
  __builtin_amdgcn_global_load_lds((gvoid_t*)g, (svoid_t*)s, 16, 0, 0);
}
// round-to-nearest-even f32 -> bf16 (finite inputs only)
__device__ __forceinline__ unsigned short f2bf(float x) {
  unsigned u = __float_as_uint(x);
  u = u + 0x7fffu + ((u >> 16) & 1u);
  return (unsigned short)(u >> 16);
}

// ---------------- codebook inverse norms ----------------
__global__ __launch_bounds__(256) void k_invc(const float* __restrict__ x,
                                              double* __restrict__ invd,
                                              float* __restrict__ invf) {
  const int lane = threadIdx.x & 63;
  const int row = blockIdx.x * 4 + (threadIdx.x >> 6);
  const float* p = x + (size_t)row * DDIM;
  float4 v0 = *(const float4*)(p + lane * 4);
  float4 v1 = *(const float4*)(p + 256 + lane * 4);
  double s = (double)v0.x * v0.x + (double)v0.y * v0.y + (double)v0.z * v0.z + (double)v0.w * v0.w
           + (double)v1.x * v1.x + (double)v1.y * v1.y + (double)v1.z * v1.z + (double)v1.w * v1.w;
  #pragma unroll
  for (int m = 1; m < 64; m <<= 1) s += __shfl_xor(s, m);
  if (lane == 0) {
    double iv = 1.0 / fmax(sqrt(s), 1e-6);
    invd[row] = iv;
    invf[row] = (float)iv;
  }
}

// ------- prep: split-to-hi fragment-tiled + per-row norm (fused) ----------
// Element (row,k) -> tile*8192 + (k>>5)*512 + ((row&15)|(((k>>3)&3)<<4))*8 + (k&7)
// Thread t: row r = t>>4, lane16 = t&15, handles 8 float4s at k4 = r*128+l16+j*16.
__global__ __launch_bounds__(256) void k_prep(const float* __restrict__ src,
                                              unsigned short* __restrict__ hi,
                                              float* __restrict__ nrm) {
  const int tile = blockIdx.x;
  const int t = threadIdx.x;
  const int r = t >> 4;
  const int l16 = t & 15;
  const float4* s4 = (const float4*)(src + (size_t)tile * 16 * DDIM);
  double ss = 0.0;
  #pragma unroll
  for (int j = 0; j < 8; ++j) {
    const int f4 = r * 128 + l16 + j * 16;
    float4 v = s4[f4];
    ss += (double)v.x * v.x + (double)v.y * v.y + (double)v.z * v.z + (double)v.w * v.w;
    const int k = (l16 + j * 16) * 4;
    const int kc = k >> 5;
    const int l = r | (((k >> 3) & 3) << 4);
    ushort4 h4;
    h4.x = f2bf(v.x); h4.y = f2bf(v.y); h4.z = f2bf(v.z); h4.w = f2bf(v.w);
    *(ushort4*)(hi + (size_t)tile * 8192 + kc * 512 + l * 8 + (k & 7)) = h4;
  }
  #pragma unroll
  for (int m = 1; m < 16; m <<= 1) ss += __shfl_xor(ss, m);
  if (l16 == 0) nrm[tile * 16 + r] = (float)sqrt(ss);
}

// ---------------- MFMA scorer: 256x256 tile, hi-only, BK=32 ----------------
// 512 thr, 8 waves; wave (wr=wid>>1, wc=wid&1) owns rows wr*64+ (64) x cols
// wc*128+ (128): acc[4][8]. LDS 64 KB: 2 bufs x {A 1024, B 1024} bf16x8 slots.
// Swizzle: pr=(bid&7)*16+(bid>>5), pc=(bid>>3)&3 (bijective; each XCD works a
// contiguous pr range so the A panel stays in its L2).
__global__ __launch_bounds__(512) void k_mfma(const unsigned short* __restrict__ AThi,
                                              const unsigned short* __restrict__ BThi,
                                              const float* __restrict__ invcf,
                                              const float* __restrict__ hnormf,
                                              float4* __restrict__ pcand,
                                              int* __restrict__ pcnt) {
  __shared__ bf16x8 lds[4096];
  const int tx = threadIdx.x;
  const int bid = blockIdx.x;
  const int pr = (bid & 7) * 16 + (bid >> 5);
  const int pc = (bid >> 3) & 3;
  const int lane = tx & 63;
  const int wid = tx >> 6;
  const int wr = wid >> 1;   // 0..3
  const int wc = wid & 1;    // 0..1

  f32x4 acc[4][8];
  #pragma unroll
  for (int m = 0; m < 4; ++m)
    #pragma unroll
    for (int n = 0; n < 8; ++n) acc[m][n] = (f32x4)(0.0f);

  // staging: thread stages A slots {tx, tx+512} and B slots {tx, tx+512};
  // slot s: subtile s>>6 (16 row/col tiles), li = s&63 -> 16B at li*8 elems.
  const int s0 = tx, s1 = tx + 512;
  const size_t a0 = (size_t)(pr * 16 + (s0 >> 6)) * 8192 + (s0 & 63) * 8;
  const size_t a1 = (size_t)(pr * 16 + (s1 >> 6)) * 8192 + (s1 & 63) * 8;
  const size_t b0 = (size_t)(pc * 16 + (s0 >> 6)) * 8192 + (s0 & 63) * 8;
  const size_t b1 = (size_t)(pc * 16 + (s1 >> 6)) * 8192 + (s1 & 63) * 8;

  // prologue: chunk 0 -> buf 0
  gl16(AThi + a0, &lds[s0]);
  gl16(AThi + a1, &lds[s1]);
  gl16(BThi + b0, &lds[1024 + s0]);
  gl16(BThi + b1, &lds[1024 + s1]);
  __syncthreads();

  int cur = 0;
  for (int kc = 0; kc < 16; ++kc) {
    if (kc < 15) {  // prefetch next chunk into alternate buffer
      const int off = (kc + 1) * 512;
      bf16x8* base = &lds[(cur ^ 1) * 2048];
      gl16(AThi + a0 + off, base + s0);
      gl16(AThi + a1 + off, base + s1);
      gl16(BThi + b0 + off, base + 1024 + s0);
      gl16(BThi + b1 + off, base + 1024 + s1);
    }
    const bf16x8* L = &lds[cur * 2048];
    bf16x8 af[4], bq[8];
    #pragma unroll
    for (int m = 0; m < 4; ++m) af[m] = L[(wr * 4 + m) * 64 + lane];
    #pragma unroll
    for (int n = 0; n < 8; ++n) bq[n] = L[1024 + (wc * 8 + n) * 64 + lane];
    #pragma unroll
    for (int m = 0; m < 4; ++m)
      #pragma unroll
      for (int n = 0; n < 8; ++n)
        acc[m][n] = __builtin_amdgcn_mfma_f32_16x16x32_bf16(af[m], bq[n], acc[m][n], 0, 0, 0);
    __syncthreads();  // prefetch landed (vmcnt drained) + readers done
    cur ^= 1;
  }

  // ---- epilogue: per-row top1/top2/cnt over two 64-col stripes ----
  const int q = lane >> 4;
  const int c16 = lane & 15;
  const int rowbase = pr * 256 + wr * 64;

  #pragma unroll
  for (int hn = 0; hn < 2; ++hn) {
    const int colbase = pc * 256 + wc * 128 + hn * 64;
    const int st = colbase >> 6;
    float invn[4];
    #pragma unroll
    for (int n4 = 0; n4 < 4; ++n4) invn[n4] = invcf[colbase + n4 * 16 + c16];

    #pragma unroll
    for (int m = 0; m < 4; ++m) {
      #pragma unroll
      for (int r = 0; r < 4; ++r) {
        const int row = rowbase + m * 16 + q * 4 + r;
        float sv[4];
        #pragma unroll
        for (int n4 = 0; n4 < 4; ++n4) sv[n4] = acc[m][hn * 4 + n4][r] * invn[n4];

        // top1 (lowest index on ties)
        float t1 = sv[0]; int i1 = colbase + c16;
        #pragma unroll
        for (int n4 = 1; n4 < 4; ++n4) {
          const int idx = colbase + n4 * 16 + c16;
          if (sv[n4] > t1) { t1 = sv[n4]; i1 = idx; }
        }
        #pragma unroll
        for (int msk = 1; msk < 16; msk <<= 1) {
          float os = __shfl_xor(t1, msk); int oi = __shfl_xor(i1, msk);
          if (os > t1 || (os == t1 && oi < i1)) { t1 = os; i1 = oi; }
        }

        const float thr = t1 - MARGIN_COEF * hnormf[row];
        int cnt = 0;
        float t2 = -3.4e38f; int i2 = 0x7fffffff;
        #pragma unroll
        for (int n4 = 0; n4 < 4; ++n4) {
          const int idx = colbase + n4 * 16 + c16;
          cnt += (sv[n4] >= thr);
          if (idx != i1 && sv[n4] > t2) { t2 = sv[n4]; i2 = idx; }
        }
        #pragma unroll
        for (int msk = 1; msk < 16; msk <<= 1) {
          cnt += __shfl_xor(cnt, msk);
          float os = __shfl_xor(t2, msk); int oi = __shfl_xor(i2, msk);
          if (os > t2 || (os == t2 && oi < i2)) { t2 = os; i2 = oi; }
        }

        if (c16 == 0) {
          pcand[(size_t)row * 16 + st] = make_float4(t1, __int_as_float(i1), t2, __int_as_float(i2));
          pcnt[(size_t)row * 16 + st] = cnt;
        }
      }
    }
  }
}

// ---------------- epilogue: fp64 rescoring + outputs ----------------
__global__ __launch_bounds__(256) void k_finalize(const float* __restrict__ h,
                                                  const float* __restrict__ cb,
                                                  const double* __restrict__ invcd,
                                                  const float* __restrict__ hnormf,
                                                  const float4* __restrict__ pcand,
                                                  const int* __restrict__ pcnt,
                                                  float* __restrict__ out_q,
                                                  float* __restrict__ out_ct,
                                                  float* __restrict__ out_ch,
                                                  float* __restrict__ out_cq,
                                                  float* __restrict__ out_idx,
                                                  double* __restrict__ lsum) {
  const int n = blockIdx.x;
  const int tx = threadIdx.x;
  const int lane = tx & 63;
  const int wv = tx >> 6;
  __shared__ double shd[8];
  __shared__ double sred[4];
  __shared__ int sidx[4];
  __shared__ float4 spc[16];
  __shared__ int sct[16];
  __shared__ int scand[34];  // [0]=nc, [1..32]=codes, [33]=rescan flags

  const int d0 = tx * 2;
  float2 hv = *(const float2*)(&h[(size_t)n * DDIM + d0]);
  double hs = (double)hv.x * hv.x + (double)hv.y * hv.y;
  #pragma unroll
  for (int m = 1; m < 64; m <<= 1) hs += __shfl_xor(hs, m);
  if (lane == 0) shd[wv] = hs;
  if (tx < 16) { spc[tx] = pcand[(size_t)n * 16 + tx]; sct[tx] = pcnt[(size_t)n * 16 + tx]; }
  __syncthreads();
  const double ih = 1.0 / fmax(sqrt(shd[0] + shd[1] + shd[2] + shd[3]), 1e-6);

  if (tx == 0) {
    float best = spc[0].x;
    #pragma unroll
    for (int t = 1; t < 16; ++t) best = fmaxf(best, spc[t].x);
    const float thr = best - MARGIN_COEF * hnormf[n];
    int nc = 0, fl = 0;
    #pragma unroll
    for (int t = 0; t < 16; ++t) {
      if (spc[t].x >= thr) scand[1 + nc++] = __float_as_int(spc[t].y);
      if (spc[t].z >= thr) {
        scand[1 + nc++] = __float_as_int(spc[t].w);
        if (sct[t] > 2) fl |= (1 << t);
      }
    }
    scand[0] = nc;
    scand[33] = fl;
  }
  __syncthreads();
  const int nc = scand[0];
  const int fl = scand[33];

  double bs = -1e300; int bi = 0x7fffffff;
  for (int ci = 0; ci < nc; ++ci) {
    const int code = scand[1 + ci];
    float2 cv = *(const float2*)(&cb[(size_t)code * DDIM + d0]);
    double p = (double)hv.x * (double)cv.x + (double)hv.y * (double)cv.y;
    #pragma unroll
    for (int m = 1; m < 64; m <<= 1) p += __shfl_xor(p, m);
    if (lane == 0) sred[wv] = p;
    __syncthreads();
    const double sc = (sred[0] + sred[1] + sred[2] + sred[3]) * invcd[code];
    if (sc > bs || (sc == bs && code < bi)) { bs = sc; bi = code; }
    __syncthreads();
  }

  if (fl) {  // pathological stripes: exact fp64 scan of 64 codes each
    for (int t = 0; t < 16; ++t) {
      if (!(fl & (1 << t))) continue;
      double wbs = -1e300; int wbi = 0x7fffffff;
      const float* hp = h + (size_t)n * DDIM + lane * 8;
      for (int j = 0; j < 16; ++j) {
        const int code = t * 64 + j * 4 + wv;
        const float* cp = cb + (size_t)code * DDIM + lane * 8;
        double p = 0.0;
        #pragma unroll
        for (int e = 0; e < 8; ++e) p = fma((double)hp[e], (double)cp[e], p);
        #pragma unroll
        for (int m = 1; m < 64; m <<= 1) p += __shfl_xor(p, m);
        const double sc = p * invcd[code];
        if (sc > wbs || (sc == wbs && code < wbi)) { wbs = sc; wbi = code; }
      }
      if (lane == 0) { sred[wv] = wbs; sidx[wv] = wbi; }
      __syncthreads();
      #pragma unroll
      for (int w = 0; w < 4; ++w) {
        const double sc = sred[w]; const int ii = sidx[w];
        if (sc > bs || (sc == bs && ii < bi)) { bs = sc; bi = ii; }
      }
      __syncthreads();
    }
  }

  if (tx == 0) out_idx[n] = (float)bi;

  const double ic = invcd[bi];
  float2 cv = *(const float2*)(&cb[(size_t)bi * DDIM + d0]);
  const double cd0 = (double)cv.x * ic, cd1 = (double)cv.y * ic;
  float2 co; co.x = (float)cd0; co.y = (float)cd1;
  const size_t ro = (size_t)n * DDIM + d0;
  *(float2*)(&out_ct[ro]) = co;
  *(float2*)(&out_ch[ro]) = co;
  *(float2*)(&out_cq[ro]) = co;

  const int qb = tx * 4;
  float4 qv;
  qv.x = (qb + 0 == bi) ? 1.0f : 0.0f;
  qv.y = (qb + 1 == bi) ? 1.0f : 0.0f;
  qv.z = (qb + 2 == bi) ? 1.0f : 0.0f;
  qv.w = (qb + 3 == bi) ? 1.0f : 0.0f;
  *(float4*)(&out_q[(size_t)n * KCODE + qb]) = qv;

  double e0 = (double)hv.x * ih - cd0;
  double e1 = (double)hv.y * ih - cd1;
  double ls = e0 * e0 + e1 * e1;
  #pragma unroll
  for (int m = 1; m < 64; m <<= 1) ls += __shfl_xor(ls, m);
  if (lane == 0) shd[4 + wv] = ls;
  __syncthreads();
  if (tx == 0) lsum[n] = shd[4] + shd[5] + shd[6] + shd[7];
}

__global__ __launch_bounds__(256) void k_loss(const double* __restrict__ lsum,
                                              float* __restrict__ out_loss) {
  const int tx = threadIdx.x;
  double s = 0.0;
  for (int i = tx; i < NROWS; i += 256) s += lsum[i];
  #pragma unroll
  for (int m = 1; m < 64; m <<= 1) s += __shfl_xor(s, m);
  __shared__ double sh[4];
  if ((tx & 63) == 0) sh[tx >> 6] = s;
  __syncthreads();
  if (tx == 0)
    out_loss[0] = (float)(1.25 * (sh[0] + sh[1] + sh[2] + sh[3]) / ((double)NROWS * (double)DDIM));
}

extern "C" void kernel_launch(void* const* d_in, const int* in_sizes, int n_in,
                              void* d_out, int out_size, void* d_ws, size_t ws_size,
                              hipStream_t stream) {
  const float* h = (const float*)d_in[0];
  const float* cb = (const float*)d_in[1];

  float* out = (float*)d_out;
  float* out_q    = out;
  float* out_ct   = out + 33554432;
  float* out_ch   = out + 50331648;
  float* out_cq   = out + 67108864;
  float* out_loss = out + 83886080;
  float* out_idx  = out + 83886081;

  char* ws = (char*)d_ws;
  unsigned short* AThi = (unsigned short*)(ws);               // 32 MB
  unsigned short* BThi = (unsigned short*)(ws + 33554432);    // 1 MB
  double* invcd  = (double*)(ws + 34603008);                  // 8 KB
  float*  invcf  = (float*)(ws + 34611200);                   // 4 KB
  float*  hnormf = (float*)(ws + 34615296);                   // 128 KB
  float*  cbnrm  = (float*)(ws + 34746368);                   // 4 KB (unused sink)
  float4* pcand  = (float4*)(ws + 34750464);                  // 8 MB
  int*    pcnt   = (int*)(ws + 43139072);                     // 2 MB
  double* lsum   = (double*)(ws + 45236224);                  // 256 KB

  k_invc<<<KCODE / 4, 256, 0, stream>>>(cb, invcd, invcf);
  k_prep<<<NROWS / 16, 256, 0, stream>>>(h, AThi, hnormf);
  k_prep<<<KCODE / 16, 256, 0, stream>>>(cb, BThi, cbnrm);
  k_mfma<<<512, 512, 0, stream>>>(AThi, BThi, invcf, hnormf, pcand, pcnt);
  k_finalize<<<NROWS, 256, 0, stream>>>(h, cb, invcd, hnormf, pcand, pcnt,
                                        out_q, out_ct, out_ch, out_cq, out_idx, lsum);
  k_loss<<<1, 256, 0, stream>>>(lsum, out_loss);
}